// Round 1
// baseline (329.477 us; speedup 1.0000x reference)
//
#include <hip/hip_runtime.h>
#include <math.h>

#define SA 8  // samples per block in conv kernel

typedef unsigned short u16;
typedef unsigned int u32;

__device__ __forceinline__ u16 f32_to_bf16(float f) {
    u32 u = __float_as_uint(f);
    u32 r = u + 0x7FFFu + ((u >> 16) & 1u);   // round-to-nearest-even
    return (u16)(r >> 16);
}

__device__ __forceinline__ u32 pack_bf16x2(u16 a, u16 b) {
    return (u32)a | ((u32)b << 16);
}

// ---------------- Kernel A: conv1 + relu + pool + conv2 + relu + pool ----------------
// h[b][c*16+ip] (bf16) written to workspace.
__global__ __launch_bounds__(256) void convs_kernel(
    const float* __restrict__ x,
    const float* __restrict__ w1, const float* __restrict__ b1,
    const float* __restrict__ w2, const float* __restrict__ b2,
    u16* __restrict__ h)
{
    __shared__ __align__(16) float sx[SA][64];
    __shared__ __align__(16) float c1p[SA][32][36]; // [s][ic][p+1], zeros at 0 and 33; stride 36 keeps rows 16B-aligned
    __shared__ __align__(16) float w2t[96][66];     // [ic*3+t][c]; pad 66 -> conflict-free staging + reads
    __shared__ float w1s[96];
    __shared__ float b1s[32];
    __shared__ float b2s[64];

    const int tid = threadIdx.x;
    const int bs  = blockIdx.x * SA;

    // stage weights
    if (tid < 96) w1s[tid] = w1[tid];
    if (tid >= 96 && tid < 128) b1s[tid - 96] = b1[tid - 96];
    if (tid >= 128 && tid < 192) b2s[tid - 128] = b2[tid - 128];
    for (int idx = tid; idx < 6144; idx += 256) {
        int c = idx / 96;
        int r = idx - c * 96;
        w2t[r][c] = w2[idx];         // transposed: [ic*3+t][c]
    }
    // stage x
    for (int idx = tid; idx < SA * 64; idx += 256) {
        int s = idx >> 6, i = idx & 63;
        sx[s][i] = x[(size_t)(bs + s) * 64 + i];
    }
    __syncthreads();

    // conv1 + relu + pool2 -> c1p[s][c][ip+1]
    for (int idx = tid; idx < SA * 32 * 32; idx += 256) {
        int s   = idx >> 10;
        int rem = idx & 1023;
        int c   = rem >> 5;
        int ip  = rem & 31;
        float wa = w1s[c * 3 + 0], wb = w1s[c * 3 + 1], wc = w1s[c * 3 + 2];
        float bb = b1s[c];
        int j = ip * 2;
        float xm1 = (j > 0)      ? sx[s][j - 1] : 0.f;
        float x0  = sx[s][j];
        float x1  = sx[s][j + 1];
        float x2  = (j + 2 < 64) ? sx[s][j + 2] : 0.f;
        float y0 = bb + wa * xm1 + wb * x0 + wc * x1;
        float y1 = bb + wa * x0  + wb * x1 + wc * x2;
        c1p[s][c][ip + 1] = fmaxf(fmaxf(y0, y1), 0.f);
    }
    // zero halo columns
    for (int idx = tid; idx < SA * 32; idx += 256) {
        int s = idx >> 5, ic = idx & 31;
        c1p[s][ic][0]  = 0.f;
        c1p[s][ic][33] = 0.f;
        c1p[s][ic][34] = 0.f;
        c1p[s][ic][35] = 0.f;
    }
    __syncthreads();

    // conv2 + relu + pool2: thread -> (sample s, channel pair c0,c0+1), all 32 pre-pool positions
    {
        const int s  = tid >> 5;          // 0..7
        const int c0 = (tid & 31) * 2;    // 0,2,..,62
        float y0[32], y1[32];
        const float bb0 = b2s[c0], bb1 = b2s[c0 + 1];
#pragma unroll
        for (int p = 0; p < 32; ++p) { y0[p] = bb0; y1[p] = bb1; }

        for (int ic = 0; ic < 32; ++ic) {
            float win[36];
            const float4* wp = (const float4*)&c1p[s][ic][0];
#pragma unroll
            for (int q = 0; q < 9; ++q) ((float4*)win)[q] = wp[q];
#pragma unroll
            for (int t = 0; t < 3; ++t) {
                float2 wv = *(const float2*)&w2t[ic * 3 + t][c0];
#pragma unroll
                for (int p = 0; p < 32; ++p) {
                    y0[p] = fmaf(wv.x, win[p + t], y0[p]);
                    y1[p] = fmaf(wv.y, win[p + t], y1[p]);
                }
            }
        }
        // pool + relu + pack bf16, vectorized store (16 bf16 = 2 x uint4 per channel)
        u32 o0[8], o1[8];
#pragma unroll
        for (int ip = 0; ip < 8; ++ip) {
            u16 a0 = f32_to_bf16(fmaxf(fmaxf(y0[4*ip+0], y0[4*ip+1]), 0.f));
            u16 a1 = f32_to_bf16(fmaxf(fmaxf(y0[4*ip+2], y0[4*ip+3]), 0.f));
            o0[ip] = pack_bf16x2(a0, a1);
            u16 c1v = f32_to_bf16(fmaxf(fmaxf(y1[4*ip+0], y1[4*ip+1]), 0.f));
            u16 c2v = f32_to_bf16(fmaxf(fmaxf(y1[4*ip+2], y1[4*ip+3]), 0.f));
            o1[ip] = pack_bf16x2(c1v, c2v);
        }
        size_t base = (size_t)(bs + s) * 1024 + (size_t)c0 * 16;
        uint4* dst = (uint4*)(h + base);
        dst[0] = make_uint4(o0[0], o0[1], o0[2], o0[3]);
        dst[1] = make_uint4(o0[4], o0[5], o0[6], o0[7]);
        dst[2] = make_uint4(o1[0], o1[1], o1[2], o1[3]);
        dst[3] = make_uint4(o1[4], o1[5], o1[6], o1[7]);
    }
}

// ---------------- quantum helpers (all indices compile-time -> registers) ----------------
template<int STRIDE>
__device__ __forceinline__ void ry_gate(float st[16], float theta) {
    float s, c;
    sincosf(theta * 0.5f, &s, &c);
#pragma unroll
    for (int i = 0; i < 16; ++i) {
        if (i & STRIDE) continue;
        float s0 = st[i], s1 = st[i | STRIDE];
        st[i]          = c * s0 - s * s1;
        st[i | STRIDE] = fmaf(s, s0, c * s1);
    }
}

template<int CS, int TS>
__device__ __forceinline__ void cnot_gate(float st[16]) {
#pragma unroll
    for (int i = 0; i < 16; ++i) {
        if ((i & CS) && !(i & TS)) {
            float tmp = st[i];
            st[i] = st[i | TS];
            st[i | TS] = tmp;
        }
    }
}

// ---------------- Kernel B: fc GEMM (64x64 tile) + pre/tanh/quantum/post/sigmoid ----------------
__global__ __launch_bounds__(256) void fc_q_kernel(
    const u16* __restrict__ h,
    const float* __restrict__ fcw, const float* __restrict__ fcb,
    const float* __restrict__ prew, const float* __restrict__ preb,
    const float* __restrict__ qp,
    const float* __restrict__ postw, const float* __restrict__ postb,
    float* __restrict__ out)
{
    __shared__ __align__(16) float hs[64][36];   // [sample][k] tile, rows 16B aligned
    __shared__ __align__(16) float wsl[32][64];  // [k][n] tile
    __shared__ __align__(16) float hfl[64][65];  // relu(fc out) for epilogue
    __shared__ float prews[256];

    const int tid = threadIdx.x;
    const int bs  = blockIdx.x * 64;
    const int tx  = tid & 15;      // output-channel group
    const int ty  = tid >> 4;      // sample group
    const int ty4 = ty * 4;
    const int tx4 = tx * 4;

    prews[tid] = prew[tid];        // 64*4 = 256 floats

    float acc[4][4];
#pragma unroll
    for (int i = 0; i < 4; ++i)
#pragma unroll
        for (int j = 0; j < 4; ++j) acc[i][j] = 0.f;

    for (int k0 = 0; k0 < 1024; k0 += 32) {
        // stage h tile: thread -> (ss = tid/4, kq = tid%4), 8 bf16 = 16B
        {
            int ss = tid >> 2, kq = tid & 3;
            const uint4* hp = (const uint4*)(h + (size_t)(bs + ss) * 1024 + k0 + kq * 8);
            uint4 raw = *hp;
            float f[8];
            u32 w0 = raw.x, w1 = raw.y, w2 = raw.z, w3 = raw.w;
            f[0] = __uint_as_float(w0 << 16); f[1] = __uint_as_float(w0 & 0xFFFF0000u);
            f[2] = __uint_as_float(w1 << 16); f[3] = __uint_as_float(w1 & 0xFFFF0000u);
            f[4] = __uint_as_float(w2 << 16); f[5] = __uint_as_float(w2 & 0xFFFF0000u);
            f[6] = __uint_as_float(w3 << 16); f[7] = __uint_as_float(w3 & 0xFFFF0000u);
            float4* d = (float4*)&hs[ss][kq * 8];
            d[0] = make_float4(f[0], f[1], f[2], f[3]);
            d[1] = make_float4(f[4], f[5], f[6], f[7]);
        }
        // stage w tile: thread -> (kk = tid/8, ng = tid%8), 8 floats
        {
            int kk = tid >> 3, ng = tid & 7;
            const float4* wp = (const float4*)(fcw + (size_t)(k0 + kk) * 64 + ng * 8);
            float4* d = (float4*)&wsl[kk][ng * 8];
            d[0] = wp[0];
            d[1] = wp[1];
        }
        __syncthreads();
#pragma unroll
        for (int kk = 0; kk < 32; ++kk) {
            float a0 = hs[ty4 + 0][kk];
            float a1 = hs[ty4 + 1][kk];
            float a2 = hs[ty4 + 2][kk];
            float a3 = hs[ty4 + 3][kk];
            float4 bv = *(const float4*)&wsl[kk][tx4];
            acc[0][0] = fmaf(a0, bv.x, acc[0][0]);
            acc[0][1] = fmaf(a0, bv.y, acc[0][1]);
            acc[0][2] = fmaf(a0, bv.z, acc[0][2]);
            acc[0][3] = fmaf(a0, bv.w, acc[0][3]);
            acc[1][0] = fmaf(a1, bv.x, acc[1][0]);
            acc[1][1] = fmaf(a1, bv.y, acc[1][1]);
            acc[1][2] = fmaf(a1, bv.z, acc[1][2]);
            acc[1][3] = fmaf(a1, bv.w, acc[1][3]);
            acc[2][0] = fmaf(a2, bv.x, acc[2][0]);
            acc[2][1] = fmaf(a2, bv.y, acc[2][1]);
            acc[2][2] = fmaf(a2, bv.z, acc[2][2]);
            acc[2][3] = fmaf(a2, bv.w, acc[2][3]);
            acc[3][0] = fmaf(a3, bv.x, acc[3][0]);
            acc[3][1] = fmaf(a3, bv.y, acc[3][1]);
            acc[3][2] = fmaf(a3, bv.z, acc[3][2]);
            acc[3][3] = fmaf(a3, bv.w, acc[3][3]);
        }
        __syncthreads();
    }

    // bias + relu -> hfl
    float bj0 = fcb[tx4 + 0], bj1 = fcb[tx4 + 1], bj2 = fcb[tx4 + 2], bj3 = fcb[tx4 + 3];
#pragma unroll
    for (int i = 0; i < 4; ++i) {
        hfl[ty4 + i][tx4 + 0] = fmaxf(acc[i][0] + bj0, 0.f);
        hfl[ty4 + i][tx4 + 1] = fmaxf(acc[i][1] + bj1, 0.f);
        hfl[ty4 + i][tx4 + 2] = fmaxf(acc[i][2] + bj2, 0.f);
        hfl[ty4 + i][tx4 + 3] = fmaxf(acc[i][3] + bj3, 0.f);
    }
    __syncthreads();

    // per-sample epilogue: pre -> tanh -> quantum circuit -> post -> sigmoid
    if (tid < 64) {
        const int s = tid;
        float qin[4];
#pragma unroll
        for (int j = 0; j < 4; ++j) {
            float a = preb[j];
#pragma unroll 8
            for (int n = 0; n < 64; ++n)
                a = fmaf(hfl[s][n], prews[n * 4 + j], a);
            qin[j] = tanhf(a) * 1.5707963267948966f;
        }

        float st[16];
#pragma unroll
        for (int i = 0; i < 16; ++i) st[i] = 0.25f;

        // initial RY layer (wire w -> bit stride 8>>w)
        ry_gate<8>(st, qin[0]);
        ry_gate<4>(st, qin[1]);
        ry_gate<2>(st, qin[2]);
        ry_gate<1>(st, qin[3]);

        for (int k = 0; k < 6; ++k) {
            cnot_gate<8, 4>(st);   // CNOT(0,1)
            cnot_gate<2, 1>(st);   // CNOT(2,3)
            cnot_gate<4, 2>(st);   // CNOT(1,2)
            ry_gate<8>(st, qp[k * 4 + 0]);
            ry_gate<4>(st, qp[k * 4 + 1]);
            ry_gate<2>(st, qp[k * 4 + 2]);
            ry_gate<1>(st, qp[k * 4 + 3]);
        }

        float z0 = 0.f, z1 = 0.f, z2 = 0.f, z3 = 0.f;
#pragma unroll
        for (int i = 0; i < 16; ++i) {
            float p = st[i] * st[i];
            z0 += (i & 8) ? -p : p;
            z1 += (i & 4) ? -p : p;
            z2 += (i & 2) ? -p : p;
            z3 += (i & 1) ? -p : p;
        }
        float t = postb[0] + z0 * postw[0] + z1 * postw[1] + z2 * postw[2] + z3 * postw[3];
        out[bs + s] = 1.f / (1.f + expf(-t));
    }
}

extern "C" void kernel_launch(void* const* d_in, const int* in_sizes, int n_in,
                              void* d_out, int out_size, void* d_ws, size_t ws_size,
                              hipStream_t stream) {
    const float* x     = (const float*)d_in[0];
    const float* w1    = (const float*)d_in[1];
    const float* b1    = (const float*)d_in[2];
    const float* w2    = (const float*)d_in[3];
    const float* b2    = (const float*)d_in[4];
    const float* fcw   = (const float*)d_in[5];
    const float* fcb   = (const float*)d_in[6];
    const float* prew  = (const float*)d_in[7];
    const float* preb  = (const float*)d_in[8];
    const float* qp    = (const float*)d_in[9];
    const float* postw = (const float*)d_in[10];
    const float* postb = (const float*)d_in[11];
    float* out = (float*)d_out;
    u16* h = (u16*)d_ws;   // 32768*1024 bf16 = 64 MiB scratch

    const int B = in_sizes[0] / 64;   // 32768

    convs_kernel<<<dim3(B / SA), dim3(256), 0, stream>>>(x, w1, b1, w2, b2, h);
    fc_q_kernel<<<dim3(B / 64), dim3(256), 0, stream>>>(h, fcw, fcb, prew, preb, qp,
                                                        postw, postb, out);
}

// Round 2
// 183.421 us; speedup vs baseline: 1.7963x; 1.7963x over previous
//
#include <hip/hip_runtime.h>
#include <math.h>

typedef unsigned short u16;
typedef unsigned int u32;
typedef __attribute__((ext_vector_type(8))) short bf16x8;   // 8 bf16 = 4 VGPR (MFMA A/B frag)
typedef __attribute__((ext_vector_type(4))) float f32x4;    // MFMA C/D frag

#define SA 8  // samples per block in conv kernel

__device__ __forceinline__ u16 f32_to_bf16(float f) {
    u32 u = __float_as_uint(f);
    u32 r = u + 0x7FFFu + ((u >> 16) & 1u);   // round-to-nearest-even
    return (u16)(r >> 16);
}
__device__ __forceinline__ float bf16_to_f32(u16 h) {
    return __uint_as_float(((u32)h) << 16);
}
__device__ __forceinline__ u32 pack2(u16 a, u16 b) { return (u32)a | ((u32)b << 16); }

// ---------------- Prep: fcw [k_ref=oc*16+op][f] -> fcwT_{hi,lo} [f][k_new=op*64+oc] bf16 split ----
__global__ __launch_bounds__(256) void prep_kernel(
    const float* __restrict__ fcw, u16* __restrict__ whi, u16* __restrict__ wlo)
{
    const int f  = blockIdx.x;         // 0..63
    const int k0 = threadIdx.x * 4;    // 0..1020
    u16 hv[4], lv[4];
#pragma unroll
    for (int i = 0; i < 4; ++i) {
        int k  = k0 + i;
        int op = k >> 6, oc = k & 63;
        float v = fcw[(size_t)(oc * 16 + op) * 64 + f];
        u16 hb = f32_to_bf16(v);
        hv[i] = hb;
        lv[i] = f32_to_bf16(v - bf16_to_f32(hb));
    }
    *(uint2*)(whi + (size_t)f * 1024 + k0) = make_uint2(pack2(hv[0], hv[1]), pack2(hv[2], hv[3]));
    *(uint2*)(wlo + (size_t)f * 1024 + k0) = make_uint2(pack2(lv[0], lv[1]), pack2(lv[2], lv[3]));
}

// ---------------- Kernel A: conv1(fp32) + pool + conv2(MFMA bf16) + pool -> h bf16 ----------------
// h global layout: h[s][op*64 + oc]  (op in 0..15, oc in 0..63)
__global__ __launch_bounds__(256, 3) void convs_kernel(
    const float* __restrict__ x,
    const float* __restrict__ w1, const float* __restrict__ b1,
    const float* __restrict__ w2, const float* __restrict__ b2,
    u16* __restrict__ h)
{
    __shared__ u16 w2r[3][64][32];       // [t][oc][ic] bf16; frag loads once/block (conflicts ok)
    __shared__ u16 c1T[SA][34][40];      // [s][p][ic] bf16, halo rows 0 & 33 zero; pad 40 -> conflict-free b128
    __shared__ u16 pool[SA][16][72];     // [s][op][oc] bf16 pooled conv2 out; pad 72 (16B-aligned rows)
    __shared__ float b2s[64];

    const int tid = threadIdx.x;
    const int bs  = blockIdx.x * SA;

    // ---- stage w2 rearranged by tap t ----
    for (int idx = tid; idx < 6144; idx += 256) {
        int oc = idx / 96;
        int k  = idx - oc * 96;
        int ic = k / 3;
        int t  = k - ic * 3;
        w2r[t][oc][ic] = f32_to_bf16(w2[idx]);
    }
    if (tid < 64) b2s[tid] = b2[tid];

    // ---- conv1 + relu + pool2 -> c1T (thread = (s, ic), full row in regs) ----
    {
        const int s = tid >> 5, ic = tid & 31;
        const float* xp = x + (size_t)(bs + s) * 64;
        float xr[64];
#pragma unroll
        for (int i = 0; i < 16; ++i) ((float4*)xr)[i] = ((const float4*)xp)[i];
        const float wa = w1[ic * 3], wb = w1[ic * 3 + 1], wc = w1[ic * 3 + 2], bb = b1[ic];
        c1T[s][0][ic]  = 0;
        c1T[s][33][ic] = 0;
#pragma unroll
        for (int p = 1; p <= 32; ++p) {
            const int j = 2 * (p - 1);
            float xm1 = (j == 0)  ? 0.f : xr[j - 1];
            float xp2 = (j == 62) ? 0.f : xr[j + 2];
            float y0 = bb + wa * xm1   + wb * xr[j]     + wc * xr[j + 1];
            float y1 = bb + wa * xr[j] + wb * xr[j + 1] + wc * xp2;
            c1T[s][p][ic] = f32_to_bf16(fmaxf(fmaxf(y0, y1), 0.f));
        }
    }
    __syncthreads();

    // ---- conv2 via MFMA: D[oc][q] = sum_t A_t[oc][ic] * B_t[ic][q],  B_t = c1T rows shifted by t
    {
        const int lane = tid & 63;
        const int wv   = tid >> 6;
        const int lr   = lane & 15;    // A: m-row / B: n-col / D: n-col
        const int lq   = lane >> 4;    // k-octet / D row-quad

        bf16x8 af[3][4];
#pragma unroll
        for (int t = 0; t < 3; ++t)
#pragma unroll
            for (int mt = 0; mt < 4; ++mt)
                af[t][mt] = *(const bf16x8*)&w2r[t][mt * 16 + lr][lq * 8];
        f32x4 bias[4];
#pragma unroll
        for (int mt = 0; mt < 4; ++mt)
            bias[mt] = *(const f32x4*)&b2s[mt * 16 + lq * 4];

        const f32x4 zero = {0.f, 0.f, 0.f, 0.f};
#pragma unroll
        for (int nt = 0; nt < 4; ++nt) {             // wave wv -> samples 2wv, 2wv+1; halves of q
            const int s  = wv * 2 + (nt >> 1);
            const int qb = (nt & 1) * 16;
            const u16* bp = &c1T[s][qb + lr][lq * 8];
            bf16x8 bf0 = *(const bf16x8*)(bp);        // t=0 : rows p = q+0
            bf16x8 bf1 = *(const bf16x8*)(bp + 40);   // t=1 : +1 row
            bf16x8 bf2 = *(const bf16x8*)(bp + 80);   // t=2 : +2 rows

            f32x4 acc[4];
#pragma unroll
            for (int mt = 0; mt < 4; ++mt) {
                acc[mt] = __builtin_amdgcn_mfma_f32_16x16x32_bf16(af[0][mt], bf0, zero, 0, 0, 0);
                acc[mt] = __builtin_amdgcn_mfma_f32_16x16x32_bf16(af[1][mt], bf1, acc[mt], 0, 0, 0);
                acc[mt] = __builtin_amdgcn_mfma_f32_16x16x32_bf16(af[2][mt], bf2, acc[mt], 0, 0, 0);
            }
            // bias + pool(cols q pairs = lane pairs) + relu + bf16 pack -> pool LDS (even lanes)
            const int op = (qb + lr) >> 1;
#pragma unroll
            for (int mt = 0; mt < 4; ++mt) {
                float v0 = acc[mt][0] + bias[mt][0];
                float v1 = acc[mt][1] + bias[mt][1];
                float v2 = acc[mt][2] + bias[mt][2];
                float v3 = acc[mt][3] + bias[mt][3];
                float p0 = fmaxf(fmaxf(v0, __shfl_xor(v0, 1)), 0.f);
                float p1 = fmaxf(fmaxf(v1, __shfl_xor(v1, 1)), 0.f);
                float p2 = fmaxf(fmaxf(v2, __shfl_xor(v2, 1)), 0.f);
                float p3 = fmaxf(fmaxf(v3, __shfl_xor(v3, 1)), 0.f);
                if (!(lane & 1)) {
                    *(uint2*)&pool[s][op][mt * 16 + lq * 4] =
                        make_uint2(pack2(f32_to_bf16(p0), f32_to_bf16(p1)),
                                   pack2(f32_to_bf16(p2), f32_to_bf16(p3)));
                }
            }
        }
    }
    __syncthreads();

    // ---- coalesced store: pool -> h global ----
#pragma unroll
    for (int it = 0; it < 4; ++it) {
        int c  = it * 256 + tid;
        int s  = c >> 7, rem = c & 127;
        int op = rem >> 3, og = rem & 7;
        uint4 v = *(const uint4*)&pool[s][op][og * 8];
        *(uint4*)(h + (size_t)(bs + s) * 1024 + op * 64 + og * 8) = v;
    }
}

// ---------------- quantum helpers ----------------
template<int STRIDE>
__device__ __forceinline__ void ry_gate(float st[16], float theta) {
    float s, c;
    sincosf(theta * 0.5f, &s, &c);
#pragma unroll
    for (int i = 0; i < 16; ++i) {
        if (i & STRIDE) continue;
        float s0 = st[i], s1 = st[i | STRIDE];
        st[i]          = c * s0 - s * s1;
        st[i | STRIDE] = fmaf(s, s0, c * s1);
    }
}
template<int CS, int TS>
__device__ __forceinline__ void cnot_gate(float st[16]) {
#pragma unroll
    for (int i = 0; i < 16; ++i) {
        if ((i & CS) && !(i & TS)) {
            float tmp = st[i]; st[i] = st[i | TS]; st[i | TS] = tmp;
        }
    }
}

// ---------------- Kernel B: fc (MFMA, LDS-free, split-bf16 weights) + quantum epilogue ----------
__global__ __launch_bounds__(256) void fc_q_kernel(
    const u16* __restrict__ h,
    const u16* __restrict__ whi, const u16* __restrict__ wlo,
    const float* __restrict__ fcb,
    const float* __restrict__ prew, const float* __restrict__ preb,
    const float* __restrict__ qp,
    const float* __restrict__ postw, const float* __restrict__ postb,
    float* __restrict__ out)
{
    __shared__ float hfl[64][68];    // relu(fc) for epilogue; pad 68
    __shared__ float prews[256];

    const int tid  = threadIdx.x;
    const int bs   = blockIdx.x * 64;
    const int wv   = tid >> 6, lane = tid & 63;
    const int lr   = lane & 15, lq = lane >> 4;

    prews[tid] = prew[tid];

    const int n0 = wv * 16;                 // wave's fc-output-feature tile
    const float bias = fcb[n0 + lr];

    f32x4 acc[4];
#pragma unroll
    for (int mt = 0; mt < 4; ++mt) acc[mt] = (f32x4){0.f, 0.f, 0.f, 0.f};

    const u16* hbase = h   + (size_t)bs * 1024 + lq * 8;
    const u16* bh    = whi + (size_t)(n0 + lr) * 1024 + lq * 8;
    const u16* bl    = wlo + (size_t)(n0 + lr) * 1024 + lq * 8;

#pragma unroll 4
    for (int kc = 0; kc < 32; ++kc) {
        bf16x8 fh = *(const bf16x8*)(bh + kc * 32);
        bf16x8 fl = *(const bf16x8*)(bl + kc * 32);
#pragma unroll
        for (int mt = 0; mt < 4; ++mt) {
            bf16x8 a = *(const bf16x8*)(hbase + (size_t)(mt * 16 + lr) * 1024 + kc * 32);
            acc[mt] = __builtin_amdgcn_mfma_f32_16x16x32_bf16(a, fh, acc[mt], 0, 0, 0);
            acc[mt] = __builtin_amdgcn_mfma_f32_16x16x32_bf16(a, fl, acc[mt], 0, 0, 0);
        }
    }
#pragma unroll
    for (int mt = 0; mt < 4; ++mt)
#pragma unroll
        for (int r = 0; r < 4; ++r)
            hfl[mt * 16 + lq * 4 + r][n0 + lr] = fmaxf(acc[mt][r] + bias, 0.f);
    __syncthreads();

    // epilogue: one 16-sample slice per wave (lanes 0..15 active)
    if (lq == 0) {
        const int s = wv * 16 + lr;
        float a0 = preb[0], a1 = preb[1], a2 = preb[2], a3 = preb[3];
#pragma unroll
        for (int ng = 0; ng < 16; ++ng) {
            float4 hv = *(const float4*)&hfl[s][ng * 4];
#pragma unroll
            for (int i = 0; i < 4; ++i) {
                float4 pw = *(const float4*)&prews[(ng * 4 + i) * 4];
                float hx = (i == 0) ? hv.x : (i == 1) ? hv.y : (i == 2) ? hv.z : hv.w;
                a0 = fmaf(hx, pw.x, a0);
                a1 = fmaf(hx, pw.y, a1);
                a2 = fmaf(hx, pw.z, a2);
                a3 = fmaf(hx, pw.w, a3);
            }
        }
        float qin0 = tanhf(a0) * 1.5707963267948966f;
        float qin1 = tanhf(a1) * 1.5707963267948966f;
        float qin2 = tanhf(a2) * 1.5707963267948966f;
        float qin3 = tanhf(a3) * 1.5707963267948966f;

        float st[16];
#pragma unroll
        for (int i = 0; i < 16; ++i) st[i] = 0.25f;

        ry_gate<8>(st, qin0);
        ry_gate<4>(st, qin1);
        ry_gate<2>(st, qin2);
        ry_gate<1>(st, qin3);
        for (int k = 0; k < 6; ++k) {
            cnot_gate<8, 4>(st);   // CNOT(0,1)
            cnot_gate<2, 1>(st);   // CNOT(2,3)
            cnot_gate<4, 2>(st);   // CNOT(1,2)
            ry_gate<8>(st, qp[k * 4 + 0]);
            ry_gate<4>(st, qp[k * 4 + 1]);
            ry_gate<2>(st, qp[k * 4 + 2]);
            ry_gate<1>(st, qp[k * 4 + 3]);
        }
        float z0 = 0.f, z1 = 0.f, z2 = 0.f, z3 = 0.f;
#pragma unroll
        for (int i = 0; i < 16; ++i) {
            float p = st[i] * st[i];
            z0 += (i & 8) ? -p : p;
            z1 += (i & 4) ? -p : p;
            z2 += (i & 2) ? -p : p;
            z3 += (i & 1) ? -p : p;
        }
        float t = postb[0] + z0 * postw[0] + z1 * postw[1] + z2 * postw[2] + z3 * postw[3];
        out[bs + s] = 1.f / (1.f + expf(-t));
    }
}

extern "C" void kernel_launch(void* const* d_in, const int* in_sizes, int n_in,
                              void* d_out, int out_size, void* d_ws, size_t ws_size,
                              hipStream_t stream) {
    const float* x     = (const float*)d_in[0];
    const float* w1    = (const float*)d_in[1];
    const float* b1    = (const float*)d_in[2];
    const float* w2    = (const float*)d_in[3];
    const float* b2    = (const float*)d_in[4];
    const float* fcw   = (const float*)d_in[5];
    const float* fcb   = (const float*)d_in[6];
    const float* prew  = (const float*)d_in[7];
    const float* preb  = (const float*)d_in[8];
    const float* qp    = (const float*)d_in[9];
    const float* postw = (const float*)d_in[10];
    const float* postb = (const float*)d_in[11];
    float* out = (float*)d_out;

    u16* h    = (u16*)d_ws;                                   // 32768*1024 bf16 = 64 MiB
    u16* fwhi = (u16*)((char*)d_ws + 67108864ULL);            // 64*1024 bf16 = 128 KiB
    u16* fwlo = fwhi + 65536;                                 // 128 KiB

    const int B = in_sizes[0] / 64;   // 32768

    prep_kernel<<<dim3(64), dim3(256), 0, stream>>>(fcw, fwhi, fwlo);
    convs_kernel<<<dim3(B / SA), dim3(256), 0, stream>>>(x, w1, b1, w2, b2, h);
    fc_q_kernel<<<dim3(B / 64), dim3(256), 0, stream>>>(h, fwhi, fwlo, fcb, prew, preb, qp,
                                                        postw, postb, out);
}

// Round 3
// 181.592 us; speedup vs baseline: 1.8144x; 1.0101x over previous
//
#include <hip/hip_runtime.h>
#include <math.h>

typedef unsigned short u16;
typedef unsigned int u32;
typedef __attribute__((ext_vector_type(8))) short bf16x8;   // 8 bf16 = 4 VGPR (MFMA A/B frag)
typedef __attribute__((ext_vector_type(4))) float f32x4;    // MFMA C/D frag

__device__ __forceinline__ u16 f32_to_bf16(float f) {
    u32 u = __float_as_uint(f);
    u32 r = u + 0x7FFFu + ((u >> 16) & 1u);   // round-to-nearest-even
    return (u16)(r >> 16);
}
__device__ __forceinline__ float bf16_to_f32(u16 h) {
    return __uint_as_float(((u32)h) << 16);
}
__device__ __forceinline__ u32 pack2(u16 a, u16 b) { return (u32)a | ((u32)b << 16); }

// ---------------- quantum gate helpers (compile-time strides -> registers) ----------------
template<int STRIDE>
__device__ __forceinline__ void ry_gate(float st[16], float theta) {
    float s, c;
    sincosf(theta * 0.5f, &s, &c);
#pragma unroll
    for (int i = 0; i < 16; ++i) {
        if (i & STRIDE) continue;
        float s0 = st[i], s1 = st[i | STRIDE];
        st[i]          = c * s0 - s * s1;
        st[i | STRIDE] = fmaf(s, s0, c * s1);
    }
}
template<int CS, int TS>
__device__ __forceinline__ void cnot_gate(float st[16]) {
#pragma unroll
    for (int i = 0; i < 16; ++i) {
        if ((i & CS) && !(i & TS)) {
            float tmp = st[i]; st[i] = st[i | TS]; st[i | TS] = tmp;
        }
    }
}

// ---------------- Prep: fcw transpose + bf16 hi/lo split, and build fixed circuit matrix M ----
// whi/wlo layout: [f][k_new = op*64 + oc], k_ref = oc*16 + op.
// Mg[i*16+j] = (fixed circuit applied to basis e_j)[i]  (circuit = 6 layers of CNOTs+RYs)
__global__ __launch_bounds__(256) void prep_kernel(
    const float* __restrict__ fcw, const float* __restrict__ qp,
    u16* __restrict__ whi, u16* __restrict__ wlo, float* __restrict__ Mg)
{
    const int f  = blockIdx.x;         // 0..63
    const int k0 = threadIdx.x * 4;    // 0..1020
    u16 hv[4], lv[4];
#pragma unroll
    for (int i = 0; i < 4; ++i) {
        int k  = k0 + i;
        int op = k >> 6, oc = k & 63;
        float v = fcw[(size_t)(oc * 16 + op) * 64 + f];
        u16 hb = f32_to_bf16(v);
        hv[i] = hb;
        lv[i] = f32_to_bf16(v - bf16_to_f32(hb));
    }
    *(uint2*)(whi + (size_t)f * 1024 + k0) = make_uint2(pack2(hv[0], hv[1]), pack2(hv[2], hv[3]));
    *(uint2*)(wlo + (size_t)f * 1024 + k0) = make_uint2(pack2(lv[0], lv[1]), pack2(lv[2], lv[3]));

    if (blockIdx.x == 0 && threadIdx.x < 16) {
        const int j = threadIdx.x;
        float st[16];
#pragma unroll
        for (int i = 0; i < 16; ++i) st[i] = (i == j) ? 1.f : 0.f;
        for (int k = 0; k < 6; ++k) {
            cnot_gate<8, 4>(st);   // CNOT(0,1)
            cnot_gate<2, 1>(st);   // CNOT(2,3)
            cnot_gate<4, 2>(st);   // CNOT(1,2)
            ry_gate<8>(st, qp[k * 4 + 0]);
            ry_gate<4>(st, qp[k * 4 + 1]);
            ry_gate<2>(st, qp[k * 4 + 2]);
            ry_gate<1>(st, qp[k * 4 + 3]);
        }
#pragma unroll
        for (int i = 0; i < 16; ++i) Mg[i * 16 + j] = st[i];
    }
}

// ---------------- Fused: conv1 -> conv2(MFMA) -> fc(MFMA) -> quantum epilogue ----------------
// 16 samples per block, 2048 blocks, 256 threads.
__global__ __launch_bounds__(256, 2) void fused_kernel(
    const float* __restrict__ x,
    const float* __restrict__ w1, const float* __restrict__ b1,
    const float* __restrict__ w2, const float* __restrict__ b2,
    const u16* __restrict__ whi, const u16* __restrict__ wlo,
    const float* __restrict__ fcb,
    const float* __restrict__ prew, const float* __restrict__ preb,
    const float* __restrict__ postw, const float* __restrict__ postb,
    const float* __restrict__ Mg,
    float* __restrict__ out)
{
    // c1T dead after conv2; hfl needed only after fc -> union saves 4.3 KB + keeps 2 blocks/CU
    __shared__ union {
        u16   c1T[16][34][40];   // [s][p][ic] bf16, halo rows 0 & 33 zero; stride 40 -> 16B-aligned rows
        float hfl[16][68];       // relu(fc) for epilogue
    } un;
    __shared__ u16   hT[16][1032];   // [s][op*64+oc] bf16 (+8 u16 pad: 4-bank row shift, 2-way reads)
    __shared__ float b2s[64];
    __shared__ float prews[256];
    __shared__ float Ms[16][17];     // fixed circuit matrix, padded

    const int tid  = threadIdx.x;
    const int bs   = blockIdx.x * 16;
    const int wv   = tid >> 6, lane = tid & 63;
    const int lr   = lane & 15, lq = lane >> 4;

    u16* w2r = &hT[0][0];   // w2 staged in hT space ([3][64][32] = 12 KB), consumed into regs before hT writes

    // ===== phase 0: stage weights + conv1 (independent buffers, single sync) =====
    for (int idx = tid; idx < 6144; idx += 256) {
        int oc = idx / 96;
        int k  = idx - oc * 96;
        int ic = k / 3;
        int t  = k - ic * 3;
        w2r[(t * 64 + oc) * 32 + ic] = f32_to_bf16(w2[idx]);   // [t][oc][ic]
    }
    if (tid < 64) b2s[tid] = b2[tid];
    prews[tid] = prew[tid];
    Ms[tid >> 4][tid & 15] = Mg[tid];

    {   // conv1 + relu + pool2 -> c1T ; thread=(s,ic), two sample groups
        const int sc = tid >> 5, ic = tid & 31;
        const float wa = w1[ic * 3], wb = w1[ic * 3 + 1], wc = w1[ic * 3 + 2], bb = b1[ic];
        for (int g = 0; g < 2; ++g) {
            const int s = sc + g * 8;
            const float* xp = x + (size_t)(bs + s) * 64;
            float xr[64];
#pragma unroll
            for (int i = 0; i < 16; ++i) ((float4*)xr)[i] = ((const float4*)xp)[i];
            un.c1T[s][0][ic]  = 0;
            un.c1T[s][33][ic] = 0;
#pragma unroll
            for (int p = 1; p <= 32; ++p) {
                const int j = 2 * (p - 1);
                float xm1 = (j == 0)  ? 0.f : xr[j - 1];
                float xp2 = (j == 62) ? 0.f : xr[j + 2];
                float y0 = bb + wa * xm1   + wb * xr[j]     + wc * xr[j + 1];
                float y1 = bb + wa * xr[j] + wb * xr[j + 1] + wc * xp2;
                un.c1T[s][p][ic] = f32_to_bf16(fmaxf(fmaxf(y0, y1), 0.f));
            }
        }
    }
    __syncthreads();

    // ===== load conv2 A-frags (w2) into regs, then hT region becomes writable =====
    bf16x8 af[3][4];
    f32x4  bias2[4];
#pragma unroll
    for (int t = 0; t < 3; ++t)
#pragma unroll
        for (int mt = 0; mt < 4; ++mt)
            af[t][mt] = *(const bf16x8*)&w2r[(t * 64 + mt * 16 + lr) * 32 + lq * 8];
#pragma unroll
    for (int mt = 0; mt < 4; ++mt)
        bias2[mt] = *(const f32x4*)&b2s[mt * 16 + lq * 4];
    __syncthreads();

    // ===== conv2 via MFMA + pool -> hT =====
    const f32x4 zero = {0.f, 0.f, 0.f, 0.f};
#pragma unroll
    for (int nt = 0; nt < 8; ++nt) {              // wave wv -> samples wv*4 .. wv*4+3, two q-halves
        const int s  = wv * 4 + (nt >> 1);
        const int qb = (nt & 1) * 16;
        const u16* bp = &un.c1T[s][qb + lr][lq * 8];
        bf16x8 bf0 = *(const bf16x8*)(bp);        // tap t=0
        bf16x8 bf1 = *(const bf16x8*)(bp + 40);   // t=1 (+1 row)
        bf16x8 bf2 = *(const bf16x8*)(bp + 80);   // t=2 (+2 rows)

        f32x4 acc[4];
#pragma unroll
        for (int mt = 0; mt < 4; ++mt) {
            acc[mt] = __builtin_amdgcn_mfma_f32_16x16x32_bf16(af[0][mt], bf0, zero, 0, 0, 0);
            acc[mt] = __builtin_amdgcn_mfma_f32_16x16x32_bf16(af[1][mt], bf1, acc[mt], 0, 0, 0);
            acc[mt] = __builtin_amdgcn_mfma_f32_16x16x32_bf16(af[2][mt], bf2, acc[mt], 0, 0, 0);
        }
        const int op = (qb + lr) >> 1;
#pragma unroll
        for (int mt = 0; mt < 4; ++mt) {
            float v0 = acc[mt][0] + bias2[mt][0];
            float v1 = acc[mt][1] + bias2[mt][1];
            float v2 = acc[mt][2] + bias2[mt][2];
            float v3 = acc[mt][3] + bias2[mt][3];
            float p0 = fmaxf(fmaxf(v0, __shfl_xor(v0, 1)), 0.f);
            float p1 = fmaxf(fmaxf(v1, __shfl_xor(v1, 1)), 0.f);
            float p2 = fmaxf(fmaxf(v2, __shfl_xor(v2, 1)), 0.f);
            float p3 = fmaxf(fmaxf(v3, __shfl_xor(v3, 1)), 0.f);
            if (!(lane & 1)) {
                *(uint2*)&hT[s][op * 64 + mt * 16 + lq * 4] =
                    make_uint2(pack2(f32_to_bf16(p0), f32_to_bf16(p1)),
                               pack2(f32_to_bf16(p2), f32_to_bf16(p3)));
            }
        }
    }
    __syncthreads();

    // ===== fc via MFMA: M=16 samples (LDS A), N=16 features per wave (global split-bf16 B) =====
    const int n0 = wv * 16;
    const float fbias = fcb[n0 + lr];
    f32x4 facc = zero;
    const u16* ab = &hT[lr][lq * 8];
    const u16* bh = whi + (size_t)(n0 + lr) * 1024 + lq * 8;
    const u16* bl = wlo + (size_t)(n0 + lr) * 1024 + lq * 8;
#pragma unroll 8
    for (int kc = 0; kc < 32; ++kc) {
        bf16x8 a  = *(const bf16x8*)(ab + kc * 32);
        bf16x8 fh = *(const bf16x8*)(bh + kc * 32);
        bf16x8 fl = *(const bf16x8*)(bl + kc * 32);
        facc = __builtin_amdgcn_mfma_f32_16x16x32_bf16(a, fh, facc, 0, 0, 0);
        facc = __builtin_amdgcn_mfma_f32_16x16x32_bf16(a, fl, facc, 0, 0, 0);
    }
    // D: row = lq*4+r = sample, col = lr = feature-within-tile (c1T reads done pre-sync -> safe)
#pragma unroll
    for (int r = 0; r < 4; ++r)
        un.hfl[lq * 4 + r][n0 + lr] = fmaxf(facc[r] + fbias, 0.f);
    __syncthreads();

    // ===== epilogue: 16 lanes/wave, 4 lanes per sample =====
    if (lane < 16) {
        const int L  = lane & 3;       // feature/row splitter
        const int sg = lane >> 2;
        const int s  = wv * 4 + sg;

        // pre matmul: partial dot over features L*16 .. L*16+15
        float a0 = 0.f, a1 = 0.f, a2 = 0.f, a3 = 0.f;
#pragma unroll
        for (int i2 = 0; i2 < 4; ++i2) {
            float4 hv = *(const float4*)&un.hfl[s][L * 16 + i2 * 4];
#pragma unroll
            for (int c = 0; c < 4; ++c) {
                int ff = L * 16 + i2 * 4 + c;
                float4 pw = *(const float4*)&prews[ff * 4];
                float hx = (c == 0) ? hv.x : (c == 1) ? hv.y : (c == 2) ? hv.z : hv.w;
                a0 = fmaf(hx, pw.x, a0);
                a1 = fmaf(hx, pw.y, a1);
                a2 = fmaf(hx, pw.z, a2);
                a3 = fmaf(hx, pw.w, a3);
            }
        }
        a0 += __shfl_xor(a0, 1); a0 += __shfl_xor(a0, 2);
        a1 += __shfl_xor(a1, 1); a1 += __shfl_xor(a1, 2);
        a2 += __shfl_xor(a2, 1); a2 += __shfl_xor(a2, 2);
        a3 += __shfl_xor(a3, 1); a3 += __shfl_xor(a3, 2);

        const float HP = 1.5707963267948966f;
        float qin[4] = { tanhf(a0 + preb[0]) * HP, tanhf(a1 + preb[1]) * HP,
                         tanhf(a2 + preb[2]) * HP, tanhf(a3 + preb[3]) * HP };

        // product init state after input RYs: amp[j] = prod_w v[w][bit_w(j)], bit_w = 8>>w
        float va[4], vb[4];
        const float RS = 0.70710678118654752f;   // 1/sqrt(2) per qubit (0.25 uniform overall)
#pragma unroll
        for (int w = 0; w < 4; ++w) {
            float sw, cw;
            sincosf(qin[w] * 0.5f, &sw, &cw);
            va[w] = (cw - sw) * RS;
            vb[w] = (sw + cw) * RS;
        }
        float sv[16];
#pragma unroll
        for (int j = 0; j < 16; ++j) {
            float t = (j & 8) ? vb[0] : va[0];
            t *= (j & 4) ? vb[1] : va[1];
            t *= (j & 2) ? vb[2] : va[2];
            t *= (j & 1) ? vb[3] : va[3];
            sv[j] = t;
        }
        // final = M @ sv ; each lane does 4 rows, partial quadratic form
        float z0 = 0.f, z1 = 0.f, z2 = 0.f, z3 = 0.f;
#pragma unroll
        for (int rr = 0; rr < 4; ++rr) {
            const int r = L * 4 + rr;
            float m = 0.f;
#pragma unroll
            for (int j = 0; j < 16; ++j) m = fmaf(Ms[r][j], sv[j], m);
            float p = m * m;
            z0 += (r & 8) ? -p : p;
            z1 += (r & 4) ? -p : p;
            z2 += (r & 2) ? -p : p;
            z3 += (r & 1) ? -p : p;
        }
        z0 += __shfl_xor(z0, 1); z0 += __shfl_xor(z0, 2);
        z1 += __shfl_xor(z1, 1); z1 += __shfl_xor(z1, 2);
        z2 += __shfl_xor(z2, 1); z2 += __shfl_xor(z2, 2);
        z3 += __shfl_xor(z3, 1); z3 += __shfl_xor(z3, 2);

        if (L == 0) {
            float t = postb[0] + z0 * postw[0] + z1 * postw[1] + z2 * postw[2] + z3 * postw[3];
            out[bs + s] = 1.f / (1.f + expf(-t));
        }
    }
}

extern "C" void kernel_launch(void* const* d_in, const int* in_sizes, int n_in,
                              void* d_out, int out_size, void* d_ws, size_t ws_size,
                              hipStream_t stream) {
    const float* x     = (const float*)d_in[0];
    const float* w1    = (const float*)d_in[1];
    const float* b1    = (const float*)d_in[2];
    const float* w2    = (const float*)d_in[3];
    const float* b2    = (const float*)d_in[4];
    const float* fcw   = (const float*)d_in[5];
    const float* fcb   = (const float*)d_in[6];
    const float* prew  = (const float*)d_in[7];
    const float* preb  = (const float*)d_in[8];
    const float* qp    = (const float*)d_in[9];
    const float* postw = (const float*)d_in[10];
    const float* postb = (const float*)d_in[11];
    float* out = (float*)d_out;

    u16*   fwhi = (u16*)d_ws;                           // 64*1024 bf16 = 128 KiB
    u16*   fwlo = fwhi + 65536;                         // 128 KiB
    float* Mg   = (float*)((char*)d_ws + 262144);       // 16*16 f32 = 1 KiB

    const int B = in_sizes[0] / 64;   // 32768

    prep_kernel<<<dim3(64), dim3(256), 0, stream>>>(fcw, qp, fwhi, fwlo, Mg);
    fused_kernel<<<dim3(B / 16), dim3(256), 0, stream>>>(x, w1, b1, w2, b2,
                                                         fwhi, fwlo, fcb, prew, preb,
                                                         postw, postb, Mg, out);
}

// Round 4
// 168.495 us; speedup vs baseline: 1.9554x; 1.0777x over previous
//
#include <hip/hip_runtime.h>
#include <math.h>

typedef unsigned short u16;
typedef unsigned int u32;
typedef __attribute__((ext_vector_type(8))) short bf16x8;   // 8 bf16 = 4 VGPR (MFMA A/B frag)
typedef __attribute__((ext_vector_type(4))) float f32x4;    // MFMA C/D frag

__device__ __forceinline__ u16 f32_to_bf16(float f) {
    u32 u = __float_as_uint(f);
    u32 r = u + 0x7FFFu + ((u >> 16) & 1u);   // round-to-nearest-even
    return (u16)(r >> 16);
}
__device__ __forceinline__ float bf16_to_f32(u16 h) {
    return __uint_as_float(((u32)h) << 16);
}
__device__ __forceinline__ u32 pack2(u16 a, u16 b) { return (u32)a | ((u32)b << 16); }

// ---------------- quantum gate helpers ----------------
template<int STRIDE>
__device__ __forceinline__ void ry_gate(float st[16], float theta) {
    float s, c;
    sincosf(theta * 0.5f, &s, &c);
#pragma unroll
    for (int i = 0; i < 16; ++i) {
        if (i & STRIDE) continue;
        float s0 = st[i], s1 = st[i | STRIDE];
        st[i]          = c * s0 - s * s1;
        st[i | STRIDE] = fmaf(s, s0, c * s1);
    }
}
template<int CS, int TS>
__device__ __forceinline__ void cnot_gate(float st[16]) {
#pragma unroll
    for (int i = 0; i < 16; ++i) {
        if ((i & CS) && !(i & TS)) {
            float tmp = st[i]; st[i] = st[i | TS]; st[i | TS] = tmp;
        }
    }
}

// ---------------- Prep: fcw transpose+split, w2->bf16 frag layout, circuit matrix M ----------
// whi/wlo: [f][k = op*64+oc] (k_ref = oc*16+op). w2b: [(t*64+oc)*32+ic] bf16.
__global__ __launch_bounds__(256) void prep_kernel(
    const float* __restrict__ fcw, const float* __restrict__ w2,
    const float* __restrict__ qp,
    u16* __restrict__ whi, u16* __restrict__ wlo,
    u16* __restrict__ w2b, float* __restrict__ Mg)
{
    const int f  = blockIdx.x;         // 0..63
    const int k0 = threadIdx.x * 4;    // 0..1020
    u16 hv[4], lv[4];
#pragma unroll
    for (int i = 0; i < 4; ++i) {
        int k  = k0 + i;
        int op = k >> 6, oc = k & 63;
        float v = fcw[(size_t)(oc * 16 + op) * 64 + f];
        u16 hb = f32_to_bf16(v);
        hv[i] = hb;
        lv[i] = f32_to_bf16(v - bf16_to_f32(hb));
    }
    *(uint2*)(whi + (size_t)f * 1024 + k0) = make_uint2(pack2(hv[0], hv[1]), pack2(hv[2], hv[3]));
    *(uint2*)(wlo + (size_t)f * 1024 + k0) = make_uint2(pack2(lv[0], lv[1]), pack2(lv[2], lv[3]));

    // w2 conversion: block b = oc slice (96 elems), thread j<96: j = ic*3+t
    if (threadIdx.x < 96) {
        const int j  = threadIdx.x;
        const int ic = j / 3, t = j - ic * 3;
        w2b[(t * 64 + f) * 32 + ic] = f32_to_bf16(w2[f * 96 + j]);
    }

    if (blockIdx.x == 0 && threadIdx.x < 16) {
        const int j = threadIdx.x;
        float st[16];
#pragma unroll
        for (int i = 0; i < 16; ++i) st[i] = (i == j) ? 1.f : 0.f;
        for (int k = 0; k < 6; ++k) {
            cnot_gate<8, 4>(st);   // CNOT(0,1)
            cnot_gate<2, 1>(st);   // CNOT(2,3)
            cnot_gate<4, 2>(st);   // CNOT(1,2)
            ry_gate<8>(st, qp[k * 4 + 0]);
            ry_gate<4>(st, qp[k * 4 + 1]);
            ry_gate<2>(st, qp[k * 4 + 2]);
            ry_gate<1>(st, qp[k * 4 + 3]);
        }
#pragma unroll
        for (int i = 0; i < 16; ++i) Mg[i * 16 + j] = st[i];
    }
}

// ---------------- Fused: conv1 -> conv2(MFMA) -> fc(MFMA) -> quantum epilogue ----------------
// 16 samples/block, 2048 blocks, 256 threads, ~50 KB LDS -> 3 blocks/CU.
// Per-sample LDS block (1384 u16 = 2768 B, stride 692 dw == 20 mod 32):
//   c1T rows: p in [0,34), stride 40 u16 (halo rows 0 & 33 zero)  [bytes 0..2719]
//   hT (aliased, written during conv2 AFTER that sample's reads): op-chunk stride 72 u16,
//   within chunk oc 0..63 linear [bytes 0..2287]
__global__ __launch_bounds__(256, 3) void fused_kernel(
    const float* __restrict__ x,
    const float* __restrict__ w1, const float* __restrict__ b1,
    const u16* __restrict__ w2b, const float* __restrict__ b2,
    const u16* __restrict__ whi, const u16* __restrict__ wlo,
    const float* __restrict__ fcb,
    const float* __restrict__ prew, const float* __restrict__ preb,
    const float* __restrict__ postw, const float* __restrict__ postb,
    const float* __restrict__ Mg,
    float* __restrict__ out)
{
    __shared__ __align__(16) u16 c1h[16 * 1384];                 // 44.3 KB c1T/hT aliased
    __shared__ __align__(16) union { float sx[16][68]; float hfl[16][68]; } un;  // 4.3 KB
    __shared__ float w1s[96];
    __shared__ float b1s[32];
    __shared__ float prews[256];
    __shared__ float Ms[16][17];

    const int tid  = threadIdx.x;
    const int bs   = blockIdx.x * 16;
    const int wv   = tid >> 6, lane = tid & 63;
    const int lr   = lane & 15, lq = lane >> 4;

    // ---- issue global A-frag / bias loads early (L2-hot, no LDS dependency) ----
    bf16x8 af[3][4];
#pragma unroll
    for (int t = 0; t < 3; ++t)
#pragma unroll
        for (int mt = 0; mt < 4; ++mt)
            af[t][mt] = *(const bf16x8*)(w2b + (size_t)(t * 64 + mt * 16 + lr) * 32 + lq * 8);
    f32x4 bias2[4];
#pragma unroll
    for (int mt = 0; mt < 4; ++mt)
        bias2[mt] = *(const f32x4*)(b2 + mt * 16 + lq * 4);

    // ---- stage small tables + x ----
    if (tid < 96) w1s[tid] = w1[tid];
    else if (tid < 128) b1s[tid - 96] = b1[tid - 96];
    prews[tid] = prew[tid];
    Ms[tid >> 4][tid & 15] = Mg[tid];
    {
        const int sr = tid >> 4, sc4 = (tid & 15) * 4;
        *(float4*)&un.sx[sr][sc4] = *(const float4*)(x + (size_t)(bs + sr) * 64 + sc4);
    }
    __syncthreads();

    // ---- conv1 + relu + pool2 -> c1T rows; thread = (s, p-slot), 2 row-groups ----
    {
        const int s1 = tid >> 4, pp = tid & 15;
        u16* sbase = c1h + s1 * 1384;
        if (pp == 0) {       // halo rows (32 u16 = 4 uint4 each)
            uint4 z = make_uint4(0, 0, 0, 0);
            uint4* z0 = (uint4*)(sbase);
            uint4* z1 = (uint4*)(sbase + 33 * 40);
            z0[0] = z; z0[1] = z; z0[2] = z; z0[3] = z;
            z1[0] = z; z1[1] = z; z1[2] = z; z1[3] = z;
        }
        const int j0 = 2 * pp, j1 = 2 * pp + 32;
        float am1 = (j0 == 0) ? 0.f : un.sx[s1][j0 - 1];
        float a0  = un.sx[s1][j0];
        float a1  = un.sx[s1][j0 + 1];
        float ap2 = un.sx[s1][j0 + 2];
        float bm1 = un.sx[s1][j1 - 1];
        float b0  = un.sx[s1][j1];
        float b1v = un.sx[s1][j1 + 1];
        float bp2 = (j1 == 62) ? 0.f : un.sx[s1][j1 + 2];

        u32 row0[16], row1[16];
#pragma unroll
        for (int ic = 0; ic < 32; ++ic) {
            float wa = w1s[ic * 3], wb = w1s[ic * 3 + 1], wc = w1s[ic * 3 + 2], bb = b1s[ic];
            float y0 = bb + wa * am1 + wb * a0 + wc * a1;
            float y1 = bb + wa * a0  + wb * a1 + wc * ap2;
            u16 v0 = f32_to_bf16(fmaxf(fmaxf(y0, y1), 0.f));
            float z0 = bb + wa * bm1 + wb * b0  + wc * b1v;
            float z1 = bb + wa * b0  + wb * b1v + wc * bp2;
            u16 v1 = f32_to_bf16(fmaxf(fmaxf(z0, z1), 0.f));
            if (ic & 1) { row0[ic >> 1] |= ((u32)v0) << 16; row1[ic >> 1] |= ((u32)v1) << 16; }
            else        { row0[ic >> 1] = v0;               row1[ic >> 1] = v1; }
        }
        uint4* d0 = (uint4*)(sbase + (1 + pp) * 40);
        d0[0] = make_uint4(row0[0], row0[1], row0[2], row0[3]);
        d0[1] = make_uint4(row0[4], row0[5], row0[6], row0[7]);
        d0[2] = make_uint4(row0[8], row0[9], row0[10], row0[11]);
        d0[3] = make_uint4(row0[12], row0[13], row0[14], row0[15]);
        uint4* d1 = (uint4*)(sbase + (17 + pp) * 40);
        d1[0] = make_uint4(row1[0], row1[1], row1[2], row1[3]);
        d1[1] = make_uint4(row1[4], row1[5], row1[6], row1[7]);
        d1[2] = make_uint4(row1[8], row1[9], row1[10], row1[11]);
        d1[3] = make_uint4(row1[12], row1[13], row1[14], row1[15]);
    }
    __syncthreads();

    // ---- conv2 via MFMA + pool -> hT (aliased into c1h; per-sample reads precede writes) ----
    const f32x4 zero = {0.f, 0.f, 0.f, 0.f};
#pragma unroll
    for (int nt = 0; nt < 8; ++nt) {              // wave wv -> samples wv*4..wv*4+3, two q-halves
        const int s  = wv * 4 + (nt >> 1);
        const int qb = (nt & 1) * 16;
        const u16* bp = c1h + s * 1384 + (qb + lr) * 40 + lq * 8;
        bf16x8 bf0 = *(const bf16x8*)(bp);        // tap t=0
        bf16x8 bf1 = *(const bf16x8*)(bp + 40);   // t=1 (+1 row)
        bf16x8 bf2 = *(const bf16x8*)(bp + 80);   // t=2 (+2 rows)

        f32x4 acc[4];
#pragma unroll
        for (int mt = 0; mt < 4; ++mt) {
            acc[mt] = __builtin_amdgcn_mfma_f32_16x16x32_bf16(af[0][mt], bf0, zero, 0, 0, 0);
            acc[mt] = __builtin_amdgcn_mfma_f32_16x16x32_bf16(af[1][mt], bf1, acc[mt], 0, 0, 0);
            acc[mt] = __builtin_amdgcn_mfma_f32_16x16x32_bf16(af[2][mt], bf2, acc[mt], 0, 0, 0);
        }
        const int op = (qb + lr) >> 1;
#pragma unroll
        for (int mt = 0; mt < 4; ++mt) {
            float v0 = acc[mt][0] + bias2[mt][0];
            float v1 = acc[mt][1] + bias2[mt][1];
            float v2 = acc[mt][2] + bias2[mt][2];
            float v3 = acc[mt][3] + bias2[mt][3];
            float p0 = fmaxf(fmaxf(v0, __shfl_xor(v0, 1)), 0.f);
            float p1 = fmaxf(fmaxf(v1, __shfl_xor(v1, 1)), 0.f);
            float p2 = fmaxf(fmaxf(v2, __shfl_xor(v2, 1)), 0.f);
            float p3 = fmaxf(fmaxf(v3, __shfl_xor(v3, 1)), 0.f);
            if (!(lane & 1)) {
                *(uint2*)(c1h + s * 1384 + op * 72 + mt * 16 + lq * 4) =
                    make_uint2(pack2(f32_to_bf16(p0), f32_to_bf16(p1)),
                               pack2(f32_to_bf16(p2), f32_to_bf16(p3)));
            }
        }
    }
    __syncthreads();

    // ---- fc via MFMA: A = hT (LDS), B = split-bf16 weights (L2 stream) ----
    const int n0 = wv * 16;
    const float fbias = fcb[n0 + lr];
    f32x4 facc = zero;
    const u16* ab = c1h + lr * 1384 + lq * 8;
    const u16* bh = whi + (size_t)(n0 + lr) * 1024 + lq * 8;
    const u16* bl = wlo + (size_t)(n0 + lr) * 1024 + lq * 8;
#pragma unroll 8
    for (int kc = 0; kc < 32; ++kc) {
        bf16x8 a  = *(const bf16x8*)(ab + (kc >> 1) * 72 + (kc & 1) * 32);
        bf16x8 fh = *(const bf16x8*)(bh + kc * 32);
        bf16x8 fl = *(const bf16x8*)(bl + kc * 32);
        facc = __builtin_amdgcn_mfma_f32_16x16x32_bf16(a, fh, facc, 0, 0, 0);
        facc = __builtin_amdgcn_mfma_f32_16x16x32_bf16(a, fl, facc, 0, 0, 0);
    }
    // D: row = lq*4+r = sample, col = lr = feature; hfl overlays sx (dead since conv1)
#pragma unroll
    for (int r = 0; r < 4; ++r)
        un.hfl[lq * 4 + r][n0 + lr] = fmaxf(facc[r] + fbias, 0.f);
    __syncthreads();

    // ---- epilogue: wave wv -> samples wv*4..+3, 4 lanes per sample ----
    if (lane < 16) {
        const int L  = lane & 3;
        const int sg = lane >> 2;
        const int s  = wv * 4 + sg;

        float a0 = 0.f, a1 = 0.f, a2 = 0.f, a3 = 0.f;
#pragma unroll
        for (int i2 = 0; i2 < 4; ++i2) {
            float4 hv = *(const float4*)&un.hfl[s][L * 16 + i2 * 4];
#pragma unroll
            for (int c = 0; c < 4; ++c) {
                int ff = L * 16 + i2 * 4 + c;
                float4 pw = *(const float4*)&prews[ff * 4];
                float hx = (c == 0) ? hv.x : (c == 1) ? hv.y : (c == 2) ? hv.z : hv.w;
                a0 = fmaf(hx, pw.x, a0);
                a1 = fmaf(hx, pw.y, a1);
                a2 = fmaf(hx, pw.z, a2);
                a3 = fmaf(hx, pw.w, a3);
            }
        }
        a0 += __shfl_xor(a0, 1); a0 += __shfl_xor(a0, 2);
        a1 += __shfl_xor(a1, 1); a1 += __shfl_xor(a1, 2);
        a2 += __shfl_xor(a2, 1); a2 += __shfl_xor(a2, 2);
        a3 += __shfl_xor(a3, 1); a3 += __shfl_xor(a3, 2);

        const float HP = 1.5707963267948966f;
        float qin[4] = { tanhf(a0 + preb[0]) * HP, tanhf(a1 + preb[1]) * HP,
                         tanhf(a2 + preb[2]) * HP, tanhf(a3 + preb[3]) * HP };

        float va[4], vb[4];
        const float RS = 0.70710678118654752f;
#pragma unroll
        for (int w = 0; w < 4; ++w) {
            float sw, cw;
            sincosf(qin[w] * 0.5f, &sw, &cw);
            va[w] = (cw - sw) * RS;
            vb[w] = (sw + cw) * RS;
        }
        float sv[16];
#pragma unroll
        for (int j = 0; j < 16; ++j) {
            float t = (j & 8) ? vb[0] : va[0];
            t *= (j & 4) ? vb[1] : va[1];
            t *= (j & 2) ? vb[2] : va[2];
            t *= (j & 1) ? vb[3] : va[3];
            sv[j] = t;
        }
        float z0 = 0.f, z1 = 0.f, z2 = 0.f, z3 = 0.f;
#pragma unroll
        for (int rr = 0; rr < 4; ++rr) {
            const int r = L * 4 + rr;
            float m = 0.f;
#pragma unroll
            for (int j = 0; j < 16; ++j) m = fmaf(Ms[r][j], sv[j], m);
            float p = m * m;
            z0 += (r & 8) ? -p : p;
            z1 += (r & 4) ? -p : p;
            z2 += (r & 2) ? -p : p;
            z3 += (r & 1) ? -p : p;
        }
        z0 += __shfl_xor(z0, 1); z0 += __shfl_xor(z0, 2);
        z1 += __shfl_xor(z1, 1); z1 += __shfl_xor(z1, 2);
        z2 += __shfl_xor(z2, 1); z2 += __shfl_xor(z2, 2);
        z3 += __shfl_xor(z3, 1); z3 += __shfl_xor(z3, 2);

        if (L == 0) {
            float t = postb[0] + z0 * postw[0] + z1 * postw[1] + z2 * postw[2] + z3 * postw[3];
            out[bs + s] = 1.f / (1.f + expf(-t));
        }
    }
}

extern "C" void kernel_launch(void* const* d_in, const int* in_sizes, int n_in,
                              void* d_out, int out_size, void* d_ws, size_t ws_size,
                              hipStream_t stream) {
    const float* x     = (const float*)d_in[0];
    const float* w1    = (const float*)d_in[1];
    const float* b1    = (const float*)d_in[2];
    const float* w2    = (const float*)d_in[3];
    const float* b2    = (const float*)d_in[4];
    const float* fcw   = (const float*)d_in[5];
    const float* fcb   = (const float*)d_in[6];
    const float* prew  = (const float*)d_in[7];
    const float* preb  = (const float*)d_in[8];
    const float* qp    = (const float*)d_in[9];
    const float* postw = (const float*)d_in[10];
    const float* postb = (const float*)d_in[11];
    float* out = (float*)d_out;

    u16*   fwhi = (u16*)d_ws;                           // 128 KiB
    u16*   fwlo = fwhi + 65536;                         // 128 KiB
    float* Mg   = (float*)((char*)d_ws + 262144);       // 1 KiB
    u16*   w2b  = (u16*)((char*)d_ws + 263168);         // 12 KiB

    const int B = in_sizes[0] / 64;   // 32768

    prep_kernel<<<dim3(64), dim3(256), 0, stream>>>(fcw, w2, qp, fwhi, fwlo, w2b, Mg);
    fused_kernel<<<dim3(B / 16), dim3(256), 0, stream>>>(x, w1, b1, w2b, b2,
                                                         fwhi, fwlo, fcb, prew, preb,
                                                         postw, postb, Mg, out);
}